// Round 1
// baseline (210.743 us; speedup 1.0000x reference)
//
#include <hip/hip_runtime.h>
#include <hip/hip_bf16.h>

typedef __attribute__((ext_vector_type(4))) float f32x4;
typedef __attribute__((ext_vector_type(8))) __bf16 bf16x8;
typedef __attribute__((ext_vector_type(4))) unsigned int u32x4;

// B=32, S=4096, E=A=512.
// out = [weighted (32*512), prob (32*4096)] fp32, total 147456.

__device__ __forceinline__ float lo_bf(unsigned int u) {
  return __builtin_bit_cast(float, u << 16);
}
__device__ __forceinline__ float hi_bf(unsigned int u) {
  return __builtin_bit_cast(float, u & 0xffff0000u);
}

// ---------- prep 1: Wt[n][k] = bf16(W_enc[k][n]) ----------
__global__ void prep_w(const float* __restrict__ W_enc, unsigned short* __restrict__ Wt) {
  int idx = blockIdx.x * 256 + threadIdx.x;   // 0..262143
  int k = idx >> 9, n = idx & 511;
  float f = W_enc[idx];
  Wt[n * 512 + k] = __builtin_bit_cast(unsigned short, (__bf16)f);
}

// ---------- prep 2: c[b][a] = dec_h[b]@W_dec[:,a] + b_dec[a] + b_enc[a] ----------
__global__ void prep_c(const float* __restrict__ dec_h, const float* __restrict__ W_dec,
                       const float* __restrict__ b_dec, const float* __restrict__ b_enc,
                       float* __restrict__ c_vec) {
  int idx = blockIdx.x * 256 + threadIdx.x;   // 0..16383
  int b = idx >> 9, a = idx & 511;
  float s = b_dec[a] + b_enc[a];
  const float* dh = dec_h + b * 512;
  for (int k = 0; k < 512; ++k) s += dh[k] * W_dec[k * 512 + a];
  c_vec[idx] = s;
}

// ---------- main: per 64-row chunk: enc_att GEMM (bf16 MFMA), relu·w_att reduce,
// ---------- block-softmax partial, exp-weighted input partial sums ----------
__global__ __launch_bounds__(256, 2) void attn_main(
    const float* __restrict__ input, const unsigned short* __restrict__ Wt,
    const float* __restrict__ c_vec, const float* __restrict__ w_att,
    float* __restrict__ att_out, float* __restrict__ m_out, float* __restrict__ pw_out) {
  __shared__ u32x4 A4[4096];                 // 64 rows x 512 bf16, XOR-swizzled (64 KB)
  __shared__ float c_lds[512];
  __shared__ float w_lds[512];
  __shared__ float red[4][64];
  __shared__ float p_lds[64];

  char* Al = (char*)A4;
  const int tid = threadIdx.x;
  const int wave = tid >> 6, lane = tid & 63;
  const int l15 = lane & 15, l4 = lane >> 4;
  const int blk = blockIdx.x;
  const int b = blk >> 6;          // 64 chunks per batch
  const int chunk = blk & 63;

  for (int i = tid; i < 512; i += 256) {
    c_lds[i] = c_vec[b * 512 + i];
    w_lds[i] = w_att[i];
  }

  // stage A: input[b, chunk*64 .. +64, :] -> bf16 LDS, swizzle byte ^= (row&7)<<4
  const float* Abase = input + (long)(b * 4096 + chunk * 64) * 512;
  #pragma unroll 4
  for (int i = 0; i < 16; ++i) {
    int ch = tid + i * 256;                  // 0..4095 16B-chunks
    int row = ch >> 6, c16 = ch & 63;
    const float4* src = (const float4*)(Abase + row * 512 + c16 * 8);
    float4 f0 = src[0], f1 = src[1];
    bf16x8 v;
    v[0] = (__bf16)f0.x; v[1] = (__bf16)f0.y; v[2] = (__bf16)f0.z; v[3] = (__bf16)f0.w;
    v[4] = (__bf16)f1.x; v[5] = (__bf16)f1.y; v[6] = (__bf16)f1.z; v[7] = (__bf16)f1.w;
    int byte = row * 1024 + ((c16 * 16) ^ ((row & 7) << 4));
    *(bf16x8*)(Al + byte) = v;
  }
  __syncthreads();

  // K-loop: acc[mi][nj] = 16x16 tile (rows mi*16.., cols (wave*8+nj)*16..)
  f32x4 acc[4][8];
  #pragma unroll
  for (int mi = 0; mi < 4; ++mi)
    #pragma unroll
    for (int nj = 0; nj < 8; ++nj) {
      f32x4 z = {0.f, 0.f, 0.f, 0.f};
      acc[mi][nj] = z;
    }

  const bf16x8* wptr[8];
  #pragma unroll
  for (int nj = 0; nj < 8; ++nj) {
    int n = (wave * 8 + nj) * 16 + l15;
    wptr[nj] = (const bf16x8*)(Wt + n * 512 + l4 * 8);
  }

  for (int kb = 0; kb < 16; ++kb) {
    bf16x8 afr[4];
    #pragma unroll
    for (int mi = 0; mi < 4; ++mi) {
      int row = mi * 16 + l15;
      int byte = row * 1024 + (((kb * 64) + l4 * 16) ^ ((row & 7) << 4));
      afr[mi] = *(const bf16x8*)(Al + byte);
    }
    #pragma unroll
    for (int nj = 0; nj < 8; ++nj) {
      bf16x8 bv = wptr[nj][kb * 4];          // Wt[n][kb*32 + l4*8 ..], L2-resident
      #pragma unroll
      for (int mi = 0; mi < 4; ++mi)
        acc[mi][nj] = __builtin_amdgcn_mfma_f32_16x16x32_bf16(afr[mi], bv, acc[mi][nj], 0, 0, 0);
    }
  }

  // epilogue: att[row] = sum_n relu(enc_att + c[n]) * w[n]
  float attp[16];
  #pragma unroll
  for (int i = 0; i < 16; ++i) attp[i] = 0.f;
  #pragma unroll
  for (int nj = 0; nj < 8; ++nj) {
    int n = (wave * 8 + nj) * 16 + l15;
    float cc = c_lds[n], ww = w_lds[n];
    #pragma unroll
    for (int mi = 0; mi < 4; ++mi)
      #pragma unroll
      for (int r = 0; r < 4; ++r)
        attp[mi * 4 + r] += fmaxf(acc[mi][nj][r] + cc, 0.f) * ww;
  }
  // reduce over the 16 lanes of each row-group (low 4 lane bits)
  #pragma unroll
  for (int off = 1; off < 16; off <<= 1)
    #pragma unroll
    for (int i = 0; i < 16; ++i)
      attp[i] += __shfl_xor(attp[i], off, 64);
  if (l15 == 0) {
    #pragma unroll
    for (int mi = 0; mi < 4; ++mi)
      #pragma unroll
      for (int r = 0; r < 4; ++r)
        red[wave][mi * 16 + l4 * 4 + r] = attp[mi * 4 + r];
  }
  __syncthreads();

  if (tid < 64) {
    float av = red[0][tid] + red[1][tid] + red[2][tid] + red[3][tid];
    att_out[b * 4096 + chunk * 64 + tid] = av;      // b_att omitted: cancels in softmax
    float m = av;
    #pragma unroll
    for (int off = 32; off >= 1; off >>= 1) m = fmaxf(m, __shfl_xor(m, off, 64));
    p_lds[tid] = expf(av - m);
    if (tid == 0) m_out[blk] = m;
  }
  __syncthreads();

  // pw[e] = sum_s exp(att_s - m_blk) * input[s][e]  (from bf16 LDS tile)
  int e = tid * 2;
  float pw0 = 0.f, pw1 = 0.f;
  for (int s = 0; s < 64; ++s) {
    float p = p_lds[s];
    unsigned int u = *(const unsigned int*)(Al + s * 1024 + ((e * 2) ^ ((s & 7) << 4)));
    pw0 += p * lo_bf(u);
    pw1 += p * hi_bf(u);
  }
  pw_out[blk * 512 + e] = pw0;
  pw_out[blk * 512 + e + 1] = pw1;
}

// ---------- finalize: per-batch global softmax + rescaled partial-sum reduction ----------
__global__ void finalize(const float* __restrict__ att, const float* __restrict__ m_blk,
                         const float* __restrict__ pw, float* __restrict__ out) {
  const int b = blockIdx.x, tid = threadIdx.x;
  const int wave = tid >> 6, lane = tid & 63;
  __shared__ float wred[4];
  __shared__ float zred[4];
  __shared__ float fac[64];

  float v[16];
  float mx = -3.4e38f;
  #pragma unroll
  for (int i = 0; i < 16; ++i) {
    v[i] = att[b * 4096 + i * 256 + tid];
    mx = fmaxf(mx, v[i]);
  }
  #pragma unroll
  for (int off = 32; off >= 1; off >>= 1) mx = fmaxf(mx, __shfl_xor(mx, off, 64));
  if (lane == 0) wred[wave] = mx;
  __syncthreads();
  mx = fmaxf(fmaxf(wred[0], wred[1]), fmaxf(wred[2], wred[3]));

  float z = 0.f;
  #pragma unroll
  for (int i = 0; i < 16; ++i) { v[i] = expf(v[i] - mx); z += v[i]; }
  #pragma unroll
  for (int off = 32; off >= 1; off >>= 1) z += __shfl_xor(z, off, 64);
  if (lane == 0) zred[wave] = z;
  __syncthreads();
  z = zred[0] + zred[1] + zred[2] + zred[3];
  float invZ = 1.f / z;

  #pragma unroll
  for (int i = 0; i < 16; ++i)
    out[16384 + b * 4096 + i * 256 + tid] = v[i] * invZ;   // prob

  if (tid < 64) fac[tid] = expf(m_blk[b * 64 + tid] - mx) * invZ;
  __syncthreads();

  int e = tid * 2;
  float w0 = 0.f, w1 = 0.f;
  for (int s = 0; s < 64; ++s) {
    float f = fac[s];
    const float* row = pw + (b * 64 + s) * 512;
    w0 += f * row[e];
    w1 += f * row[e + 1];
  }
  out[b * 512 + e] = w0;                                    // weighted
  out[b * 512 + e + 1] = w1;
}

extern "C" void kernel_launch(void* const* d_in, const int* in_sizes, int n_in,
                              void* d_out, int out_size, void* d_ws, size_t ws_size,
                              hipStream_t stream) {
  const float* input = (const float*)d_in[0];
  const float* dec_h = (const float*)d_in[1];
  const float* W_enc = (const float*)d_in[2];
  const float* b_enc = (const float*)d_in[3];
  const float* W_dec = (const float*)d_in[4];
  const float* b_dec = (const float*)d_in[5];
  const float* w_att = (const float*)d_in[6];
  // d_in[7] = b_att: constant shift of logits, cancels in softmax.
  float* out = (float*)d_out;

  char* ws = (char*)d_ws;
  unsigned short* Wt = (unsigned short*)(ws);           // 512 KB  bf16 W_enc^T [n][k]
  float* c_vec = (float*)(ws + 524288);                 // 64 KB   dec_att + b_enc
  float* att   = (float*)(ws + 589824);                 // 512 KB  logits [32][4096]
  float* m_b   = (float*)(ws + 1114112);                // 8 KB    per-block max
  float* pw    = (float*)(ws + 1122304);                // 4 MB    partial weighted [2048][512]

  hipLaunchKernelGGL(prep_w, dim3(1024), dim3(256), 0, stream, W_enc, Wt);
  hipLaunchKernelGGL(prep_c, dim3(64), dim3(256), 0, stream, dec_h, W_dec, b_dec, b_enc, c_vec);
  hipLaunchKernelGGL(attn_main, dim3(2048), dim3(256), 0, stream, input, Wt, c_vec, w_att, att, m_b, pw);
  hipLaunchKernelGGL(finalize, dim3(32), dim3(256), 0, stream, att, m_b, pw, out);
}

// Round 2
// 124.968 us; speedup vs baseline: 1.6864x; 1.6864x over previous
//
#include <hip/hip_runtime.h>
#include <hip/hip_bf16.h>

typedef __attribute__((ext_vector_type(4))) float f32x4;
typedef __attribute__((ext_vector_type(8))) __bf16 bf16x8;
typedef __attribute__((ext_vector_type(4))) unsigned int u32x4;

// B=32, S=4096, E=A=512.
// out = [weighted (32*512), prob (32*4096)] fp32, total 147456.

__device__ __forceinline__ float lo_bf(unsigned int u) {
  return __builtin_bit_cast(float, u << 16);
}
__device__ __forceinline__ float hi_bf(unsigned int u) {
  return __builtin_bit_cast(float, u & 0xffff0000u);
}

// ---------- prep 1: fragment-ordered bf16 W_enc^T ----------
// Wf[((ntile*16 + kb)*64 + lane)*8 + j] = bf16(W_enc[kb*32 + (lane>>4)*8 + j][ntile*16 + (lane&15)])
// so the main kernel's per-wave B load is one contiguous 1KB block.
__global__ void prep_w(const float* __restrict__ W_enc, unsigned short* __restrict__ Wf) {
  int idx = blockIdx.x * 256 + threadIdx.x;   // 0..32767
  int lane = idx & 63;
  int grp = idx >> 6;                         // ntile*16 + kb
  int ntile = grp >> 4, kb = grp & 15;
  int n = ntile * 16 + (lane & 15);
  int k0 = kb * 32 + (lane >> 4) * 8;
  unsigned short* dst = Wf + idx * 8;
  #pragma unroll
  for (int j = 0; j < 8; ++j) {
    float f = W_enc[(k0 + j) * 512 + n];
    dst[j] = __builtin_bit_cast(unsigned short, (__bf16)f);
  }
}

// ---------- prep 2: c[b][a] = dec_h[b]@W_dec[:,a] + b_dec[a] + b_enc[a] ----------
__global__ void prep_c(const float* __restrict__ dec_h, const float* __restrict__ W_dec,
                       const float* __restrict__ b_dec, const float* __restrict__ b_enc,
                       float* __restrict__ c_vec) {
  int idx = blockIdx.x * 256 + threadIdx.x;   // 0..16383
  int b = idx >> 9, a = idx & 511;
  float s = b_dec[a] + b_enc[a];
  const float* dh = dec_h + b * 512;
  for (int k = 0; k < 512; ++k) s += dh[k] * W_dec[k * 512 + a];
  c_vec[idx] = s;
}

// ---------- main: 512 threads (8 waves), 64-row chunk ----------
__global__ __launch_bounds__(512, 4) void attn_main(
    const float* __restrict__ input, const unsigned short* __restrict__ Wf,
    const float* __restrict__ c_vec, const float* __restrict__ w_att,
    float* __restrict__ att_out, float* __restrict__ m_out, float* __restrict__ pw_out) {
  __shared__ u32x4 A4[4096];                 // 64 rows x 512 bf16, XOR-swizzled (64 KB)
  __shared__ float c_lds[512];
  __shared__ float w_lds[512];
  __shared__ float red[8][64];
  __shared__ float p_lds[64];

  char* Al = (char*)A4;
  float* redf = &red[0][0];                  // 512-float scratch, reused in pw phase
  const int tid = threadIdx.x;
  const int wave = tid >> 6, lane = tid & 63;
  const int l15 = lane & 15, l4 = lane >> 4;
  const int blk = blockIdx.x;
  const int b = blk >> 6;                    // 64 chunks per batch
  const int chunk = blk & 63;

  if (tid < 512) {
    c_lds[tid] = c_vec[b * 512 + tid];
    w_lds[tid] = w_att[tid];
  }

  // stage A: input[b, chunk*64 .. +64, :] -> bf16 LDS, swizzle byte ^= (row&7)<<4
  // phase 1: issue all global loads; phase 2: convert + LDS write.
  const float* Abase = input + (long)(b * 4096 + chunk * 64) * 512;
  float4 f[8][2];
  #pragma unroll
  for (int i = 0; i < 8; ++i) {
    int ch = tid + i * 512;                  // 0..4095 16B-chunks
    int row = ch >> 6, c16 = ch & 63;
    const float4* src = (const float4*)(Abase + row * 512 + c16 * 8);
    f[i][0] = src[0];
    f[i][1] = src[1];
  }
  #pragma unroll
  for (int i = 0; i < 8; ++i) {
    int ch = tid + i * 512;
    int row = ch >> 6, c16 = ch & 63;
    bf16x8 v;
    v[0] = (__bf16)f[i][0].x; v[1] = (__bf16)f[i][0].y;
    v[2] = (__bf16)f[i][0].z; v[3] = (__bf16)f[i][0].w;
    v[4] = (__bf16)f[i][1].x; v[5] = (__bf16)f[i][1].y;
    v[6] = (__bf16)f[i][1].z; v[7] = (__bf16)f[i][1].w;
    int byte = row * 1024 + ((c16 * 16) ^ ((row & 7) << 4));
    *(bf16x8*)(Al + byte) = v;
  }
  __syncthreads();

  // K-loop: wave handles n-tiles wave*4 .. wave*4+3, rows 0..63 (mi 0..3)
  f32x4 acc[4][4];
  #pragma unroll
  for (int mi = 0; mi < 4; ++mi)
    #pragma unroll
    for (int nj = 0; nj < 4; ++nj) {
      f32x4 z = {0.f, 0.f, 0.f, 0.f};
      acc[mi][nj] = z;
    }

  const bf16x8* Wfp = (const bf16x8*)Wf;
  const int w4 = wave * 4;

  for (int kb = 0; kb < 16; ++kb) {
    bf16x8 bv[4];
    #pragma unroll
    for (int nj = 0; nj < 4; ++nj)
      bv[nj] = Wfp[((w4 + nj) * 16 + kb) * 64 + lane];   // contiguous 1KB per wave
    bf16x8 afr[4];
    #pragma unroll
    for (int mi = 0; mi < 4; ++mi) {
      int row = mi * 16 + l15;
      int byte = row * 1024 + (((kb * 64) + l4 * 16) ^ ((row & 7) << 4));
      afr[mi] = *(const bf16x8*)(Al + byte);
    }
    #pragma unroll
    for (int nj = 0; nj < 4; ++nj)
      #pragma unroll
      for (int mi = 0; mi < 4; ++mi)
        acc[mi][nj] = __builtin_amdgcn_mfma_f32_16x16x32_bf16(afr[mi], bv[nj], acc[mi][nj], 0, 0, 0);
  }

  // epilogue: att[row] = sum_n relu(enc_att + c[n]) * w[n]
  float attp[16];
  #pragma unroll
  for (int i = 0; i < 16; ++i) attp[i] = 0.f;
  #pragma unroll
  for (int nj = 0; nj < 4; ++nj) {
    int n = (w4 + nj) * 16 + l15;
    float cc = c_lds[n], ww = w_lds[n];
    #pragma unroll
    for (int mi = 0; mi < 4; ++mi)
      #pragma unroll
      for (int r = 0; r < 4; ++r)
        attp[mi * 4 + r] += fmaxf(acc[mi][nj][r] + cc, 0.f) * ww;
  }
  // reduce over the 16 col-lanes (low 4 lane bits)
  #pragma unroll
  for (int off = 1; off < 16; off <<= 1)
    #pragma unroll
    for (int i = 0; i < 16; ++i)
      attp[i] += __shfl_xor(attp[i], off, 64);
  if (l15 == 0) {
    #pragma unroll
    for (int mi = 0; mi < 4; ++mi)
      #pragma unroll
      for (int r = 0; r < 4; ++r)
        red[wave][mi * 16 + l4 * 4 + r] = attp[mi * 4 + r];
  }
  __syncthreads();

  if (tid < 64) {
    float av = red[0][tid] + red[1][tid] + red[2][tid] + red[3][tid]
             + red[4][tid] + red[5][tid] + red[6][tid] + red[7][tid];
    att_out[b * 4096 + chunk * 64 + tid] = av;      // b_att omitted: cancels in softmax
    float m = av;
    #pragma unroll
    for (int off = 32; off >= 1; off >>= 1) m = fmaxf(m, __shfl_xor(m, off, 64));
    p_lds[tid] = expf(av - m);
    if (tid == 0) m_out[blk] = m;
  }
  __syncthreads();

  // pw[e] = sum_s exp(att_s - m_blk) * input[s][e]; split rows over h = tid>>8
  const int c2 = (tid & 255) * 2;
  const int h = tid >> 8;
  float pw0 = 0.f, pw1 = 0.f;
  #pragma unroll 8
  for (int i = 0; i < 32; ++i) {
    int s = h * 32 + i;
    float p = p_lds[s];
    unsigned int u = *(const unsigned int*)(Al + s * 1024 + ((c2 * 2) ^ ((s & 7) << 4)));
    pw0 += p * lo_bf(u);
    pw1 += p * hi_bf(u);
  }
  if (h == 1) { redf[c2] = pw0; redf[c2 + 1] = pw1; }
  __syncthreads();
  if (h == 0) {
    pw_out[blk * 512 + c2]     = pw0 + redf[c2];
    pw_out[blk * 512 + c2 + 1] = pw1 + redf[c2 + 1];
  }
}

// ---------- finalize: per-batch global softmax + rescaled partial-sum reduction ----------
__global__ void finalize(const float* __restrict__ att, const float* __restrict__ m_blk,
                         const float* __restrict__ pw, float* __restrict__ out) {
  const int b = blockIdx.x, tid = threadIdx.x;
  const int wave = tid >> 6, lane = tid & 63;
  __shared__ float wred[4];
  __shared__ float zred[4];
  __shared__ float fac[64];

  float v[16];
  float mx = -3.4e38f;
  #pragma unroll
  for (int i = 0; i < 16; ++i) {
    v[i] = att[b * 4096 + i * 256 + tid];
    mx = fmaxf(mx, v[i]);
  }
  #pragma unroll
  for (int off = 32; off >= 1; off >>= 1) mx = fmaxf(mx, __shfl_xor(mx, off, 64));
  if (lane == 0) wred[wave] = mx;
  __syncthreads();
  mx = fmaxf(fmaxf(wred[0], wred[1]), fmaxf(wred[2], wred[3]));

  float z = 0.f;
  #pragma unroll
  for (int i = 0; i < 16; ++i) { v[i] = expf(v[i] - mx); z += v[i]; }
  #pragma unroll
  for (int off = 32; off >= 1; off >>= 1) z += __shfl_xor(z, off, 64);
  if (lane == 0) zred[wave] = z;
  __syncthreads();
  z = zred[0] + zred[1] + zred[2] + zred[3];
  float invZ = 1.f / z;

  #pragma unroll
  for (int i = 0; i < 16; ++i)
    out[16384 + b * 4096 + i * 256 + tid] = v[i] * invZ;   // prob

  if (tid < 64) fac[tid] = expf(m_blk[b * 64 + tid] - mx) * invZ;
  __syncthreads();

  int e = tid * 2;
  float w0 = 0.f, w1 = 0.f;
  for (int s = 0; s < 64; ++s) {
    float f = fac[s];
    const float* row = pw + (b * 64 + s) * 512;
    w0 += f * row[e];
    w1 += f * row[e + 1];
  }
  out[b * 512 + e] = w0;                                    // weighted
  out[b * 512 + e + 1] = w1;
}

extern "C" void kernel_launch(void* const* d_in, const int* in_sizes, int n_in,
                              void* d_out, int out_size, void* d_ws, size_t ws_size,
                              hipStream_t stream) {
  const float* input = (const float*)d_in[0];
  const float* dec_h = (const float*)d_in[1];
  const float* W_enc = (const float*)d_in[2];
  const float* b_enc = (const float*)d_in[3];
  const float* W_dec = (const float*)d_in[4];
  const float* b_dec = (const float*)d_in[5];
  const float* w_att = (const float*)d_in[6];
  // d_in[7] = b_att: constant shift of logits, cancels in softmax.
  float* out = (float*)d_out;

  char* ws = (char*)d_ws;
  unsigned short* Wf = (unsigned short*)(ws);           // 512 KB  fragment-ordered bf16 W_enc^T
  float* c_vec = (float*)(ws + 524288);                 // 64 KB   dec_att + b_enc + b_dec
  float* att   = (float*)(ws + 589824);                 // 512 KB  logits [32][4096]
  float* m_b   = (float*)(ws + 1114112);                // 8 KB    per-block max
  float* pw    = (float*)(ws + 1122304);                // 4 MB    partial weighted [2048][512]

  hipLaunchKernelGGL(prep_w, dim3(128), dim3(256), 0, stream, W_enc, Wf);
  hipLaunchKernelGGL(prep_c, dim3(64), dim3(256), 0, stream, dec_h, W_dec, b_dec, b_enc, c_vec);
  hipLaunchKernelGGL(attn_main, dim3(2048), dim3(512), 0, stream, input, Wf, c_vec, w_att, att, m_b, pw);
  hipLaunchKernelGGL(finalize, dim3(32), dim3(256), 0, stream, att, m_b, pw, out);
}